// Round 3
// baseline (663.094 us; speedup 1.0000x reference)
//
#include <hip/hip_runtime.h>
#include <stdint.h>

#define COLS 16384
#define POOLCAP 256
typedef unsigned long long u64;
typedef float vf4 __attribute__((ext_vector_type(4)));

// Order-preserving float32 -> uint32 mapping (ascending float == ascending uint).
__device__ __forceinline__ uint32_t f2key(float x) {
  uint32_t u = __float_as_uint(x);
  u ^= (uint32_t)((int32_t)u >> 31) | 0x80000000u;
  return u;
}

__global__ __launch_bounds__(256, 4) void KNNC_20272245637217_kernel(
    const float* __restrict__ dist,
    const int* __restrict__ labels,
    int* __restrict__ out) {
  const int wave = threadIdx.x >> 6;   // 4 waves/block, one row each
  const int lane = threadIdx.x & 63;
  const int row  = blockIdx.x * 4 + wave;

  __shared__ u64 poolK[4][POOLCAP];    // (sortable value bits << 32) | column idx
  __shared__ int cnt[4];
  if (threadIdx.x < 4) cnt[threadIdx.x] = 0;
  __syncthreads();

  const vf4* __restrict__ rp = (const vf4*)(dist + (size_t)row * COLS);

  // Row = 16 chunks of 256 float4 (1024 floats). Five rotating 4-wide register
  // buffers keep 16-20 loads (256-320 B/lane) in flight at all times.
  vf4 A[4], B[4], C[4], D[4], E[4];
#define L4(c, buf) { _Pragma("unroll") \
  for (int u = 0; u < 4; ++u) \
    (buf)[u] = __builtin_nontemporal_load(rp + (c)*256 + u*64 + lane); }
#define MIN4(buf) { _Pragma("unroll") \
  for (int u = 0; u < 4; ++u) \
    m = fminf(m, fminf(fminf((buf)[u].x,(buf)[u].y), fminf((buf)[u].z,(buf)[u].w))); }

  L4(0, A) L4(1, B) L4(2, C) L4(3, D) L4(4, E)   // 20 loads in flight

  // ---- Stage A: lane-min over first 4096 elements (chunks 0-3) ----
  float m = __builtin_inff();
  MIN4(A) MIN4(B) MIN4(C) MIN4(D)                // chunk 4 stays in flight

  // ---- T = exact 16th smallest of the 64 lane minima (bitonic, 21 stages).
  // Valid bound: the 16 smallest lane-minima are 16 distinct row elements <= T.
  // Pool size ~ mean 64, std ~14 -> POOLCAP 256 is ~14 sigma. Loads for chunk 4
  // remain outstanding through this serial shuffle chain.
  float v = m;
  #pragma unroll
  for (int k = 2; k <= 64; k <<= 1) {
    #pragma unroll
    for (int j = k >> 1; j >= 1; j >>= 1) {
      float o = __shfl_xor(v, j);
      bool keepMin = (((lane & j) == 0) == ((lane & k) == 0));
      v = keepMin ? fminf(v, o) : fmaxf(v, o);
    }
  }
  const float T = __shfl(v, 15);

#define PUSH(x, c) { if ((x) <= T) { \
    int _s = atomicAdd(&cnt[wave], 1); \
    if (_s < POOLCAP) poolK[wave][_s] = (((u64)f2key(x)) << 32) | (u64)(uint32_t)(c); } }
#define P4(buf, c) { _Pragma("unroll") \
  for (int u = 0; u < 4; ++u) { \
    vf4 w = (buf)[u]; \
    float mn = fminf(fminf(w.x, w.y), fminf(w.z, w.w)); \
    if (mn <= T) { \
      int col = (c)*1024 + u*256 + lane*4; \
      PUSH(w.x, col) PUSH(w.y, col+1) PUSH(w.z, col+2) PUSH(w.w, col+3) \
    } } }

  // ---- Stage B: 5-deep rotating process/prefetch pipeline ----
  P4(A,0)  L4(5,A)   P4(B,1)  L4(6,B)   P4(C,2)  L4(7,C)
  P4(D,3)  L4(8,D)   P4(E,4)  L4(9,E)   P4(A,5)  L4(10,A)
  P4(B,6)  L4(11,B)  P4(C,7)  L4(12,C)  P4(D,8)  L4(13,D)
  P4(E,9)  L4(14,E)  P4(A,10) L4(15,A)
  P4(B,11) P4(C,12) P4(D,13) P4(E,14) P4(A,15)

  __syncthreads();

  // ---- Exact top-16 extraction (u64 keys reproduce top_k's index tie-break) ----
  int C2 = cnt[wave];
  if (C2 > POOLCAP) C2 = POOLCAP;   // defensive; C2 >= 16 guaranteed by T

  u64 key[4];
  #pragma unroll
  for (int t = 0; t < 4; ++t) {
    int p = lane + 64 * t;
    key[t] = (p < C2) ? poolK[wave][p] : ~0ULL;
  }

  u64 myWin = ~0ULL;
  for (int r = 0; r < 16; ++r) {
    u64 k = key[0];
    k = (key[1] < k) ? key[1] : k;
    k = (key[2] < k) ? key[2] : k;
    k = (key[3] < k) ? key[3] : k;
    #pragma unroll
    for (int off = 32; off >= 1; off >>= 1) {
      u64 o = __shfl_xor(k, off);
      k = (o < k) ? o : k;
    }
    if (lane == r) myWin = k;           // lane r records the r-th smallest
    #pragma unroll
    for (int t = 0; t < 4; ++t)
      if (key[t] == k) key[t] = ~0ULL;  // keys unique (idx in low bits)
  }

  // ---- Majority vote over the 16 winners' labels ----
  int myLabel = 0;
  if (lane < 16) myLabel = labels[(uint32_t)myWin];  // low 32 bits = column idx

  int c = 0;
  #pragma unroll
  for (int s = 0; s < 16; ++s) {
    int ls = __shfl(myLabel, s);
    c += (ls == myLabel) ? 1 : 0;
  }
  // maximize count, then minimize label (argmax-first semantics)
  int vkey = (lane < 16) ? ((c << 7) | (127 - myLabel)) : 0;
  #pragma unroll
  for (int off = 32; off >= 1; off >>= 1) {
    int o = __shfl_xor(vkey, off);
    vkey = (o > vkey) ? o : vkey;
  }
  if (lane == 0) out[row] = 127 - (vkey & 127);
}

extern "C" void kernel_launch(void* const* d_in, const int* in_sizes, int n_in,
                              void* d_out, int out_size, void* d_ws, size_t ws_size,
                              hipStream_t stream) {
  const float* dist   = (const float*)d_in[0];
  const int*   labels = (const int*)d_in[1];
  int*         out    = (int*)d_out;
  const int rows = out_size;          // 8192
  KNNC_20272245637217_kernel<<<rows / 4, 256, 0, stream>>>(dist, labels, out);
}